// Round 2
// baseline (3311.354 us; speedup 1.0000x reference)
//
#include <hip/hip_runtime.h>

// CRAFT OHEM loss, round 2.
// Radix select on float bit patterns; counts-only histograms (sums recovered by
// register accumulation in the following pass), 4-way replicated LDS bins to
// kill same-address RMW serialization, ballot-compaction of the T1-bin
// candidates so stage 2->3 needs no third full scan.

constexpr int   BATCH   = 32;
constexpr int   NPS     = 768 * 768;            // 589824
constexpr int   CH2     = BATCH * 2;            // 64
constexpr long  PIX_ALL = (long)BATCH * NPS;
constexpr int   EPB     = 8192;                 // pixels per block
constexpr int   BX      = NPS / EPB;            // 72
constexpr float POS_THR_F = 0.1f;
constexpr unsigned TOPK_NO_POS = 500u;
constexpr int   CAP     = 131072;               // compact buffer per channel

// ---------------------------------------------------------------------------
// Pass 1: loss + positive stats + stage-1 COUNT histogram (512 bins, 4 replicas)
// ---------------------------------------------------------------------------
__global__ __launch_bounds__(256, 4) void k_pass1(
    const float4* __restrict__ pred4,
    const float4* __restrict__ reg4,
    const float4* __restrict__ aff4,
    unsigned* __restrict__ h1c,
    unsigned* __restrict__ pcnt, float* __restrict__ psum,
    float4* __restrict__ lossR4, float4* __restrict__ lossA4, int writeLoss)
{
    __shared__ unsigned sc0[512 * 4], sc1[512 * 4];
    __shared__ unsigned wpc[8];
    __shared__ float    wps[8];
    for (int j = threadIdx.x; j < 2048; j += 256) { sc0[j] = 0u; sc1[j] = 0u; }
    __syncthreads();

    const int  b   = blockIdx.y;
    const int  tid = threadIdx.x;
    const int  rep = tid & 3;
    constexpr int ITERS = EPB / 1024;            // 8; 4 pixels/thread/iter
    long idx4 = (((long)b * NPS + (long)blockIdx.x * EPB) >> 2) + tid;

    unsigned pc0 = 0, pc1 = 0;
    float    ps0 = 0.f, ps1 = 0.f;

    float4 r = reg4[idx4], a = aff4[idx4];
    float4 pA = pred4[idx4 * 2], pB = pred4[idx4 * 2 + 1];

    for (int i = 0; i < ITERS; ++i) {
        float4 rn, an, pAn, pBn;
        if (i + 1 < ITERS) {
            const long nx = idx4 + 256;
            rn = reg4[nx]; an = aff4[nx]; pAn = pred4[nx * 2]; pBn = pred4[nx * 2 + 1];
        }
        float4 lr, la;
#define DO_PIX(RR, AA, PG, PA, LR, LA) do {                                   \
        float d0 = (PG) - (RR); float v0 = d0 * d0;                           \
        bool pos0 = (RR) >= POS_THR_F;                                        \
        if (pos0) { pc0++; ps0 += v0; }                                       \
        else { unsigned ky = __float_as_uint(v0) >> 21;                       \
               if (ky > 511u) ky = 511u;                                      \
               atomicAdd(&sc0[(ky << 2) + rep], 1u); }                        \
        LR = pos0 ? -1.0f : v0;                                               \
        float d1 = (PA) - (AA); float v1 = d1 * d1;                           \
        bool pos1 = (AA) >= POS_THR_F;                                        \
        if (pos1) { pc1++; ps1 += v1; }                                       \
        else { unsigned ky = __float_as_uint(v1) >> 21;                       \
               if (ky > 511u) ky = 511u;                                      \
               atomicAdd(&sc1[(ky << 2) + rep], 1u); }                        \
        LA = pos1 ? -1.0f : v1;                                               \
    } while (0)
        DO_PIX(r.x, a.x, pA.x, pA.y, lr.x, la.x);
        DO_PIX(r.y, a.y, pA.z, pA.w, lr.y, la.y);
        DO_PIX(r.z, a.z, pB.x, pB.y, lr.z, la.z);
        DO_PIX(r.w, a.w, pB.z, pB.w, lr.w, la.w);
#undef DO_PIX
        if (writeLoss) { lossR4[idx4] = lr; lossA4[idx4] = la; }
        idx4 += 256; r = rn; a = an; pA = pAn; pB = pBn;
    }
    __syncthreads();

    for (int j = tid; j < 512; j += 256) {
        unsigned c0 = sc0[j*4] + sc0[j*4+1] + sc0[j*4+2] + sc0[j*4+3];
        if (c0) atomicAdd(&h1c[(b*2+0)*512 + j], c0);
        unsigned c1 = sc1[j*4] + sc1[j*4+1] + sc1[j*4+2] + sc1[j*4+3];
        if (c1) atomicAdd(&h1c[(b*2+1)*512 + j], c1);
    }
    for (int o = 32; o > 0; o >>= 1) {
        pc0 += __shfl_down(pc0, o); ps0 += __shfl_down(ps0, o);
        pc1 += __shfl_down(pc1, o); ps1 += __shfl_down(ps1, o);
    }
    const int wid = tid >> 6, lane = tid & 63;
    if (lane == 0) { wpc[wid] = pc0; wps[wid] = ps0; wpc[4+wid] = pc1; wps[4+wid] = ps1; }
    __syncthreads();
    if (tid == 0) {
        unsigned t0 = 0, t1 = 0; float s0 = 0.f, s1 = 0.f;
        for (int q = 0; q < 4; ++q) { t0 += wpc[q]; s0 += wps[q]; t1 += wpc[4+q]; s1 += wps[4+q]; }
        atomicAdd(&pcnt[b*2+0], t0); unsafeAtomicAdd(&psum[b*2+0], s0);
        atomicAdd(&pcnt[b*2+1], t1); unsafeAtomicAdd(&psum[b*2+1], s1);
    }
}

// ---------------------------------------------------------------------------
// counts-only block suffix select (256 threads)
// ---------------------------------------------------------------------------
template<int NBINS>
__device__ __forceinline__ void select_counts(
    const unsigned* __restrict__ cnt, unsigned k,
    unsigned& outBin, unsigned& outRem)
{
    constexpr int PER = NBINS / 256;
    const int t = threadIdx.x;
    unsigned lc[PER];
#pragma unroll
    for (int j = 0; j < PER; ++j) lc[j] = cnt[t*PER + j];
    unsigned lsum = 0;
#pragma unroll
    for (int j = 0; j < PER; ++j) lsum += lc[j];

    __shared__ unsigned part[256];
    __shared__ unsigned s_bin, s_rem;
    part[t] = lsum;
    __syncthreads();
    for (int off = 1; off < 256; off <<= 1) {
        unsigned v = (t + off < 256) ? part[t + off] : 0u;
        __syncthreads();
        part[t] += v;
        __syncthreads();
    }
    unsigned cum = (t + 1 < 256) ? part[t + 1] : 0u;
#pragma unroll
    for (int j = PER - 1; j >= 0; --j) {
        unsigned c = lc[j];
        if (cum < k && k <= cum + c) { s_bin = (unsigned)(t * PER + j); s_rem = k - cum; }
        cum += c;
    }
    __syncthreads();
    outBin = s_bin; outRem = s_rem;
}

// counts + float-sum select (for final stage)
template<int NBINS>
__device__ __forceinline__ void select_counts_sums(
    const unsigned* __restrict__ cnt, const float* __restrict__ sums,
    unsigned k, unsigned& outBin, unsigned& outRem, double& outSum)
{
    constexpr int PER = NBINS / 256;
    const int t = threadIdx.x;
    unsigned lc[PER]; float lf[PER];
#pragma unroll
    for (int j = 0; j < PER; ++j) { lc[j] = cnt[t*PER + j]; lf[j] = sums[t*PER + j]; }
    unsigned lsum = 0;
#pragma unroll
    for (int j = 0; j < PER; ++j) lsum += lc[j];

    __shared__ unsigned part[256];
    __shared__ unsigned s_bin, s_rem;
    __shared__ double   wsum[4];
    part[t] = lsum;
    __syncthreads();
    for (int off = 1; off < 256; off <<= 1) {
        unsigned v = (t + off < 256) ? part[t + off] : 0u;
        __syncthreads();
        part[t] += v;
        __syncthreads();
    }
    unsigned cum = (t + 1 < 256) ? part[t + 1] : 0u;
#pragma unroll
    for (int j = PER - 1; j >= 0; --j) {
        unsigned c = lc[j];
        if (cum < k && k <= cum + c) { s_bin = (unsigned)(t * PER + j); s_rem = k - cum; }
        cum += c;
    }
    __syncthreads();
    const unsigned bin = s_bin;
    double ds = 0.0;
#pragma unroll
    for (int j = 0; j < PER; ++j)
        if ((unsigned)(t * PER + j) > bin) ds += (double)lf[j];
    for (int o = 32; o > 0; o >>= 1) ds += __shfl_down(ds, o);
    const int wid = t >> 6, lane = t & 63;
    if (lane == 0) wsum[wid] = ds;
    __syncthreads();
    if (t == 0) ds = wsum[0] + wsum[1] + wsum[2] + wsum[3];
    outBin = bin; outRem = s_rem; outSum = ds;
}

__global__ __launch_bounds__(256) void k_scan1(
    const unsigned* __restrict__ h1c,
    const unsigned* __restrict__ pcnt, const float* __restrict__ psum,
    unsigned* __restrict__ T1, unsigned* __restrict__ rem1,
    unsigned* __restrict__ kk, float* __restrict__ posi)
{
    const int idx = blockIdx.x;
    const unsigned p  = pcnt[idx];
    const unsigned nn = (unsigned)NPS - p;
    const unsigned k  = p ? ((nn < 3u*p) ? nn : 3u*p) : TOPK_NO_POS;
    if (threadIdx.x == 0) {
        kk[idx]   = k;
        posi[idx] = p ? (psum[idx] / (float)p) : 0.0f;
    }
    if (k == 0u) {
        if (threadIdx.x == 0) { T1[idx] = 0xFFFFFFFFu; rem1[idx] = 0u; }
        return;
    }
    unsigned bin, rem;
    select_counts<512>(h1c + idx*512, k, bin, rem);
    if (threadIdx.x == 0) { T1[idx] = bin; rem1[idx] = rem; }
}

// ---------------------------------------------------------------------------
// Pass 2: register-sum of elements above T1 bin; stage-2 count histogram and
// ballot-compaction of elements inside the T1 bin.
// ---------------------------------------------------------------------------
__device__ __forceinline__ void p2_val(
    float v, unsigned t1, unsigned* __restrict__ sc, float& rs,
    float* __restrict__ cbuf_ch, unsigned* __restrict__ ccnt_ch,
    int lane, int compactMode)
{
    const bool neg = v >= 0.0f;
    const unsigned bt  = __float_as_uint(v);
    const unsigned key = bt >> 21;
    const bool match = neg && (key == t1);
    if (neg) {
        if (key > t1) rs += v;
        else if (match) atomicAdd(&sc[(bt >> 10) & 2047u], 1u);
    }
    if (compactMode) {
        const unsigned long long m = __ballot(match);
        if (match) {
            const int ldr = __ffsll((unsigned long long)m) - 1;
            const unsigned pre = (unsigned)__popcll(m & ((1ull << lane) - 1ull));
            unsigned basei = 0;
            if (lane == ldr) basei = atomicAdd(ccnt_ch, (unsigned)__popcll(m));
            basei = __shfl(basei, ldr);
            const unsigned ix = basei + pre;
            if (ix < (unsigned)CAP) cbuf_ch[ix] = v;
        }
    }
}

__global__ __launch_bounds__(256, 4) void k_pass2(
    const float4* __restrict__ pred4,
    const float4* __restrict__ reg4,
    const float4* __restrict__ aff4,
    const float4* __restrict__ lossR4, const float4* __restrict__ lossA4, int haveLoss,
    const unsigned* __restrict__ T1,
    unsigned* __restrict__ h2c, double* __restrict__ sumAbove,
    float* __restrict__ cbuf, unsigned* __restrict__ ccnt, int compactMode)
{
    __shared__ unsigned sc0[2048], sc1[2048];
    __shared__ float    wred[8];
    for (int j = threadIdx.x; j < 2048; j += 256) { sc0[j] = 0u; sc1[j] = 0u; }
    __syncthreads();

    const int b = blockIdx.y;
    const unsigned t1r = T1[b*2+0], t1a = T1[b*2+1];
    const int tid = threadIdx.x, lane = tid & 63;
    float* cb0 = cbuf + (size_t)(b*2+0) * CAP;
    float* cb1 = cbuf + (size_t)(b*2+1) * CAP;
    unsigned* cc0 = ccnt + b*2+0;
    unsigned* cc1 = ccnt + b*2+1;
    float rs0 = 0.f, rs1 = 0.f;

    constexpr int ITERS = EPB / 1024;
    long idx4 = (((long)b * NPS + (long)blockIdx.x * EPB) >> 2) + tid;
    for (int i = 0; i < ITERS; ++i, idx4 += 256) {
        float4 vr, va;
        if (haveLoss) { vr = lossR4[idx4]; va = lossA4[idx4]; }
        else {
            const float4 r  = reg4[idx4];
            const float4 a  = aff4[idx4];
            const float4 pA = pred4[idx4*2];
            const float4 pB = pred4[idx4*2+1];
            float d;
            d = pA.x - r.x; vr.x = (r.x >= POS_THR_F) ? -1.0f : d*d;
            d = pA.z - r.y; vr.y = (r.y >= POS_THR_F) ? -1.0f : d*d;
            d = pB.x - r.z; vr.z = (r.z >= POS_THR_F) ? -1.0f : d*d;
            d = pB.z - r.w; vr.w = (r.w >= POS_THR_F) ? -1.0f : d*d;
            d = pA.y - a.x; va.x = (a.x >= POS_THR_F) ? -1.0f : d*d;
            d = pA.w - a.y; va.y = (a.y >= POS_THR_F) ? -1.0f : d*d;
            d = pB.y - a.z; va.z = (a.z >= POS_THR_F) ? -1.0f : d*d;
            d = pB.w - a.w; va.w = (a.w >= POS_THR_F) ? -1.0f : d*d;
        }
        p2_val(vr.x, t1r, sc0, rs0, cb0, cc0, lane, compactMode);
        p2_val(vr.y, t1r, sc0, rs0, cb0, cc0, lane, compactMode);
        p2_val(vr.z, t1r, sc0, rs0, cb0, cc0, lane, compactMode);
        p2_val(vr.w, t1r, sc0, rs0, cb0, cc0, lane, compactMode);
        p2_val(va.x, t1a, sc1, rs1, cb1, cc1, lane, compactMode);
        p2_val(va.y, t1a, sc1, rs1, cb1, cc1, lane, compactMode);
        p2_val(va.z, t1a, sc1, rs1, cb1, cc1, lane, compactMode);
        p2_val(va.w, t1a, sc1, rs1, cb1, cc1, lane, compactMode);
    }
    __syncthreads();

    for (int j = tid; j < 2048; j += 256) {
        unsigned c0 = sc0[j];
        if (c0) atomicAdd(&h2c[(b*2+0)*2048 + j], c0);
        unsigned c1 = sc1[j];
        if (c1) atomicAdd(&h2c[(b*2+1)*2048 + j], c1);
    }
    for (int o = 32; o > 0; o >>= 1) { rs0 += __shfl_down(rs0, o); rs1 += __shfl_down(rs1, o); }
    const int wid = tid >> 6;
    if (lane == 0) { wred[wid] = rs0; wred[4+wid] = rs1; }
    __syncthreads();
    if (tid == 0) {
        float s0 = wred[0]+wred[1]+wred[2]+wred[3];
        float s1 = wred[4]+wred[5]+wred[6]+wred[7];
        unsafeAtomicAdd(&sumAbove[b*2+0], (double)s0);
        unsafeAtomicAdd(&sumAbove[b*2+1], (double)s1);
    }
}

__global__ __launch_bounds__(256) void k_scan2(
    const unsigned* __restrict__ h2c,
    const unsigned* __restrict__ T1, const unsigned* __restrict__ rem1,
    unsigned* __restrict__ T2, unsigned* __restrict__ rem2)
{
    const int idx = blockIdx.x;
    if (T1[idx] == 0xFFFFFFFFu) {
        if (threadIdx.x == 0) { T2[idx] = 0xFFFFFFFFu; rem2[idx] = 0u; }
        return;
    }
    unsigned bin, rem;
    select_counts<2048>(h2c + idx*2048, rem1[idx], bin, rem);
    if (threadIdx.x == 0) { T2[idx] = bin; rem2[idx] = rem; }
}

// ---------------------------------------------------------------------------
// Pass 3 (compact): per-channel; candidates all have key == T1 already.
// ---------------------------------------------------------------------------
__global__ __launch_bounds__(256) void k_pass3_compact(
    const float* __restrict__ cbuf, const unsigned* __restrict__ ccnt,
    const unsigned* __restrict__ T2,
    unsigned* __restrict__ h3c, float* __restrict__ h3s,
    double* __restrict__ sumMid)
{
    const int ch = blockIdx.x;
    const unsigned cnt = ccnt[ch];
    if (cnt > (unsigned)CAP) return;            // overflow -> k_pass3_full owns it
    __shared__ unsigned sc[1024];
    __shared__ float    ss[1024];
    __shared__ float    wred[4];
    for (int j = threadIdx.x; j < 1024; j += 256) { sc[j] = 0u; ss[j] = 0.f; }
    __syncthreads();

    const unsigned t2 = T2[ch];
    const float* buf = cbuf + (size_t)ch * CAP;
    float rs = 0.f;
    for (unsigned i = threadIdx.x; i < cnt; i += 256) {
        const float v = buf[i];
        const unsigned bt = __float_as_uint(v);
        const unsigned s2 = (bt >> 10) & 2047u;
        if (s2 > t2) rs += v;
        else if (s2 == t2) { atomicAdd(&sc[bt & 1023u], 1u); unsafeAtomicAdd(&ss[bt & 1023u], v); }
    }
    __syncthreads();
    for (int j = threadIdx.x; j < 1024; j += 256) {
        unsigned c = sc[j];
        if (c) { atomicAdd(&h3c[ch*1024 + j], c); unsafeAtomicAdd(&h3s[ch*1024 + j], ss[j]); }
    }
    for (int o = 32; o > 0; o >>= 1) rs += __shfl_down(rs, o);
    const int wid = threadIdx.x >> 6, lane = threadIdx.x & 63;
    if (lane == 0) wred[wid] = rs;
    __syncthreads();
    if (threadIdx.x == 0)
        unsafeAtomicAdd(&sumMid[ch], (double)(wred[0]+wred[1]+wred[2]+wred[3]));
}

// Fallback full scan: only processes channels that overflowed (or all channels
// when compaction is unavailable). Normally exits immediately.
__global__ __launch_bounds__(256, 4) void k_pass3_full(
    const float4* __restrict__ pred4,
    const float4* __restrict__ reg4,
    const float4* __restrict__ aff4,
    const float4* __restrict__ lossR4, const float4* __restrict__ lossA4, int haveLoss,
    const unsigned* __restrict__ T1, const unsigned* __restrict__ T2,
    const unsigned* __restrict__ ccnt, int compactMode,
    unsigned* __restrict__ h3c, float* __restrict__ h3s,
    double* __restrict__ sumMid)
{
    const int b = blockIdx.y;
    const bool f0 = (!compactMode) || (ccnt[b*2+0] > (unsigned)CAP);
    const bool f1 = (!compactMode) || (ccnt[b*2+1] > (unsigned)CAP);
    if (!f0 && !f1) return;

    __shared__ unsigned sc0[1024], sc1[1024];
    __shared__ float    ss0[1024], ss1[1024];
    __shared__ float    wred[8];
    for (int j = threadIdx.x; j < 1024; j += 256) { sc0[j]=0u; sc1[j]=0u; ss0[j]=0.f; ss1[j]=0.f; }
    __syncthreads();

    const unsigned t1r = T1[b*2+0], t2r = T2[b*2+0];
    const unsigned t1a = T1[b*2+1], t2a = T2[b*2+1];
    const int tid = threadIdx.x;
    float rs0 = 0.f, rs1 = 0.f;

    constexpr int ITERS = EPB / 1024;
    long idx4 = (((long)b * NPS + (long)blockIdx.x * EPB) >> 2) + tid;
    for (int i = 0; i < ITERS; ++i, idx4 += 256) {
        float4 vr, va;
        if (haveLoss) { vr = lossR4[idx4]; va = lossA4[idx4]; }
        else {
            const float4 r  = reg4[idx4];
            const float4 a  = aff4[idx4];
            const float4 pA = pred4[idx4*2];
            const float4 pB = pred4[idx4*2+1];
            float d;
            d = pA.x - r.x; vr.x = (r.x >= POS_THR_F) ? -1.0f : d*d;
            d = pA.z - r.y; vr.y = (r.y >= POS_THR_F) ? -1.0f : d*d;
            d = pB.x - r.z; vr.z = (r.z >= POS_THR_F) ? -1.0f : d*d;
            d = pB.z - r.w; vr.w = (r.w >= POS_THR_F) ? -1.0f : d*d;
            d = pA.y - a.x; va.x = (a.x >= POS_THR_F) ? -1.0f : d*d;
            d = pA.w - a.y; va.y = (a.y >= POS_THR_F) ? -1.0f : d*d;
            d = pB.y - a.z; va.z = (a.z >= POS_THR_F) ? -1.0f : d*d;
            d = pB.w - a.w; va.w = (a.w >= POS_THR_F) ? -1.0f : d*d;
        }
#define DO3(V, T1V, T2V, SC, SS, RS, EN) do {                                 \
        if (EN && (V) >= 0.0f) { unsigned bt = __float_as_uint(V);            \
            if ((bt >> 21) == (T1V)) { unsigned s2 = (bt >> 10) & 2047u;      \
                if (s2 > (T2V)) RS += (V);                                    \
                else if (s2 == (T2V)) { atomicAdd(&SC[bt & 1023u], 1u);       \
                    unsafeAtomicAdd(&SS[bt & 1023u], (V)); } } } } while (0)
        DO3(vr.x, t1r, t2r, sc0, ss0, rs0, f0); DO3(vr.y, t1r, t2r, sc0, ss0, rs0, f0);
        DO3(vr.z, t1r, t2r, sc0, ss0, rs0, f0); DO3(vr.w, t1r, t2r, sc0, ss0, rs0, f0);
        DO3(va.x, t1a, t2a, sc1, ss1, rs1, f1); DO3(va.y, t1a, t2a, sc1, ss1, rs1, f1);
        DO3(va.z, t1a, t2a, sc1, ss1, rs1, f1); DO3(va.w, t1a, t2a, sc1, ss1, rs1, f1);
#undef DO3
    }
    __syncthreads();
    for (int j = tid; j < 1024; j += 256) {
        if (f0) { unsigned c = sc0[j];
            if (c) { atomicAdd(&h3c[(b*2+0)*1024 + j], c); unsafeAtomicAdd(&h3s[(b*2+0)*1024 + j], ss0[j]); } }
        if (f1) { unsigned c = sc1[j];
            if (c) { atomicAdd(&h3c[(b*2+1)*1024 + j], c); unsafeAtomicAdd(&h3s[(b*2+1)*1024 + j], ss1[j]); } }
    }
    for (int o = 32; o > 0; o >>= 1) { rs0 += __shfl_down(rs0, o); rs1 += __shfl_down(rs1, o); }
    const int wid = tid >> 6, lane = tid & 63;
    if (lane == 0) { wred[wid] = rs0; wred[4+wid] = rs1; }
    __syncthreads();
    if (tid == 0) {
        if (f0) unsafeAtomicAdd(&sumMid[b*2+0], (double)(wred[0]+wred[1]+wred[2]+wred[3]));
        if (f1) unsafeAtomicAdd(&sumMid[b*2+1], (double)(wred[4]+wred[5]+wred[6]+wred[7]));
    }
}

__global__ __launch_bounds__(256) void k_scan3(
    const unsigned* __restrict__ h3c, const float* __restrict__ h3s,
    const unsigned* __restrict__ T1, const unsigned* __restrict__ T2,
    const unsigned* __restrict__ rem2,
    const unsigned* __restrict__ kk, const float* __restrict__ posi,
    const double* __restrict__ sumAbove, const double* __restrict__ sumMid,
    float* __restrict__ contrib)
{
    const int idx = blockIdx.x;
    const unsigned k = kk[idx];
    if (k == 0u) {
        if (threadIdx.x == 0) contrib[idx] = posi[idx];
        return;
    }
    unsigned bin, rem; double s3;
    select_counts_sums<1024>(h3c + idx*1024, h3s + idx*1024, rem2[idx], bin, rem, s3);
    if (threadIdx.x == 0) {
        const float t = __uint_as_float((T1[idx] << 21) | (T2[idx] << 10) | bin);
        const double nega = (sumAbove[idx] + sumMid[idx] + s3 + (double)rem * (double)t)
                            / (double)k;
        contrib[idx] = (float)((double)posi[idx] + nega);
    }
}

__global__ void k_reduce(const float* __restrict__ contrib, float* __restrict__ out)
{
    double v = (double)contrib[threadIdx.x];
    for (int o = 32; o > 0; o >>= 1) v += __shfl_down(v, o);
    if (threadIdx.x == 0) out[0] = (float)(v / (double)BATCH);
}

// ---------------------------------------------------------------------------
extern "C" void kernel_launch(void* const* d_in, const int* in_sizes, int n_in,
                              void* d_out, int out_size, void* d_ws, size_t ws_size,
                              hipStream_t stream)
{
    (void)in_sizes; (void)n_in; (void)out_size;
    const float4* pred4 = (const float4*)d_in[0];
    const float4* reg4  = (const float4*)d_in[1];
    const float4* aff4  = (const float4*)d_in[2];

    char* w = (char*)d_ws;
    unsigned* h1c  = (unsigned*)w;                        // 64*512
    unsigned* h2c  = h1c + (size_t)CH2 * 512;             // 64*2048
    unsigned* h3c  = h2c + (size_t)CH2 * 2048;            // 64*1024
    float*    h3s  = (float*)(h3c + (size_t)CH2 * 1024);  // 64*1024
    unsigned* pcnt = (unsigned*)(h3s + (size_t)CH2 * 1024);
    float*    psum = (float*)(pcnt + CH2);
    unsigned* T1   = (unsigned*)(psum + CH2);
    unsigned* T2   = T1 + CH2;
    unsigned* rem1 = T2 + CH2;
    unsigned* rem2 = rem1 + CH2;
    unsigned* kk   = rem2 + CH2;
    float*    posi = (float*)(kk + CH2);
    float*    contrib = posi + CH2;
    unsigned* ccnt = (unsigned*)(contrib + CH2);
    double*   sumAbove = (double*)(ccnt + CH2);           // 8B aligned
    double*   sumMid   = sumAbove + CH2;
    const size_t hdr_bytes = (size_t)((char*)(sumMid + CH2) - w);   // ~1.2 MB

    const size_t loss_off   = (size_t)4 << 20;
    const size_t loss_bytes = (size_t)PIX_ALL * 2 * sizeof(float);  // 151 MB
    const int haveLoss = (ws_size >= loss_off + loss_bytes) ? 1 : 0;
    float4* lossR4 = (float4*)(w + loss_off);
    float4* lossA4 = (float4*)(w + loss_off + (size_t)PIX_ALL * sizeof(float));

    const size_t cbuf_off   = haveLoss ? (loss_off + loss_bytes) : loss_off;
    const size_t cbuf_bytes = (size_t)CH2 * CAP * sizeof(float);    // 33.5 MB
    const int compactMode = (ws_size >= cbuf_off + cbuf_bytes) ? 1 : 0;
    float* cbuf = (float*)(w + cbuf_off);

    hipMemsetAsync(d_ws, 0, hdr_bytes, stream);

    dim3 grid(BX, BATCH);
    k_pass1<<<grid, 256, 0, stream>>>(pred4, reg4, aff4, h1c, pcnt, psum,
                                      lossR4, lossA4, haveLoss);
    k_scan1<<<CH2, 256, 0, stream>>>(h1c, pcnt, psum, T1, rem1, kk, posi);
    k_pass2<<<grid, 256, 0, stream>>>(pred4, reg4, aff4, lossR4, lossA4, haveLoss,
                                      T1, h2c, sumAbove, cbuf, ccnt, compactMode);
    k_scan2<<<CH2, 256, 0, stream>>>(h2c, T1, rem1, T2, rem2);
    if (compactMode)
        k_pass3_compact<<<CH2, 256, 0, stream>>>(cbuf, ccnt, T2, h3c, h3s, sumMid);
    k_pass3_full<<<grid, 256, 0, stream>>>(pred4, reg4, aff4, lossR4, lossA4, haveLoss,
                                           T1, T2, ccnt, compactMode, h3c, h3s, sumMid);
    k_scan3<<<CH2, 256, 0, stream>>>(h3c, h3s, T1, T2, rem2, kk, posi,
                                     sumAbove, sumMid, contrib);
    k_reduce<<<1, 64, 0, stream>>>(contrib, (float*)d_out);
}

// Round 3
// 460.366 us; speedup vs baseline: 7.1929x; 7.1929x over previous
//
#include <hip/hip_runtime.h>

// CRAFT OHEM loss, round 3.
// R2 -> R3: pass2 compaction reservation moved from contended global atomics
// (the 2949us disaster) to LDS staging: wave-ballot leader does ds_add_rtn on a
// block-local counter, block flushes once per channel with a single global
// atomic + coalesced burst write.

constexpr int   BATCH   = 32;
constexpr int   NPS     = 768 * 768;            // 589824
constexpr int   CH2     = BATCH * 2;            // 64
constexpr long  PIX_ALL = (long)BATCH * NPS;
constexpr int   EPB     = 8192;                 // pixels per block
constexpr int   BX      = NPS / EPB;            // 72
constexpr float POS_THR_F = 0.1f;
constexpr unsigned TOPK_NO_POS = 500u;
constexpr int   CAP     = 131072;               // global compact buffer per channel
constexpr int   CAPB    = 1024;                 // LDS staging per channel per block

// ---------------------------------------------------------------------------
// Pass 1: loss + positive stats + stage-1 COUNT histogram (512 bins, 4 replicas)
// ---------------------------------------------------------------------------
__global__ __launch_bounds__(256, 4) void k_pass1(
    const float4* __restrict__ pred4,
    const float4* __restrict__ reg4,
    const float4* __restrict__ aff4,
    unsigned* __restrict__ h1c,
    unsigned* __restrict__ pcnt, float* __restrict__ psum,
    float4* __restrict__ lossR4, float4* __restrict__ lossA4, int writeLoss)
{
    __shared__ unsigned sc0[512 * 4], sc1[512 * 4];
    __shared__ unsigned wpc[8];
    __shared__ float    wps[8];
    for (int j = threadIdx.x; j < 2048; j += 256) { sc0[j] = 0u; sc1[j] = 0u; }
    __syncthreads();

    const int  b   = blockIdx.y;
    const int  tid = threadIdx.x;
    const int  rep = tid & 3;
    constexpr int ITERS = EPB / 1024;            // 8
    long idx4 = (((long)b * NPS + (long)blockIdx.x * EPB) >> 2) + tid;

    unsigned pc0 = 0, pc1 = 0;
    float    ps0 = 0.f, ps1 = 0.f;

    float4 r = reg4[idx4], a = aff4[idx4];
    float4 pA = pred4[idx4 * 2], pB = pred4[idx4 * 2 + 1];

    for (int i = 0; i < ITERS; ++i) {
        float4 rn, an, pAn, pBn;
        if (i + 1 < ITERS) {
            const long nx = idx4 + 256;
            rn = reg4[nx]; an = aff4[nx]; pAn = pred4[nx * 2]; pBn = pred4[nx * 2 + 1];
        }
        float4 lr, la;
#define DO_PIX(RR, AA, PG, PA, LR, LA) do {                                   \
        float d0 = (PG) - (RR); float v0 = d0 * d0;                           \
        bool pos0 = (RR) >= POS_THR_F;                                        \
        if (pos0) { pc0++; ps0 += v0; }                                       \
        else { unsigned ky = __float_as_uint(v0) >> 21;                       \
               atomicAdd(&sc0[(ky << 2) + rep], 1u); }                        \
        LR = pos0 ? -1.0f : v0;                                               \
        float d1 = (PA) - (AA); float v1 = d1 * d1;                           \
        bool pos1 = (AA) >= POS_THR_F;                                        \
        if (pos1) { pc1++; ps1 += v1; }                                       \
        else { unsigned ky = __float_as_uint(v1) >> 21;                       \
               atomicAdd(&sc1[(ky << 2) + rep], 1u); }                        \
        LA = pos1 ? -1.0f : v1;                                               \
    } while (0)
        DO_PIX(r.x, a.x, pA.x, pA.y, lr.x, la.x);
        DO_PIX(r.y, a.y, pA.z, pA.w, lr.y, la.y);
        DO_PIX(r.z, a.z, pB.x, pB.y, lr.z, la.z);
        DO_PIX(r.w, a.w, pB.z, pB.w, lr.w, la.w);
#undef DO_PIX
        if (writeLoss) { lossR4[idx4] = lr; lossA4[idx4] = la; }
        idx4 += 256; r = rn; a = an; pA = pAn; pB = pBn;
    }
    __syncthreads();

    for (int j = tid; j < 512; j += 256) {
        unsigned c0 = sc0[j*4] + sc0[j*4+1] + sc0[j*4+2] + sc0[j*4+3];
        if (c0) atomicAdd(&h1c[(b*2+0)*512 + j], c0);
        unsigned c1 = sc1[j*4] + sc1[j*4+1] + sc1[j*4+2] + sc1[j*4+3];
        if (c1) atomicAdd(&h1c[(b*2+1)*512 + j], c1);
    }
    for (int o = 32; o > 0; o >>= 1) {
        pc0 += __shfl_down(pc0, o); ps0 += __shfl_down(ps0, o);
        pc1 += __shfl_down(pc1, o); ps1 += __shfl_down(ps1, o);
    }
    const int wid = tid >> 6, lane = tid & 63;
    if (lane == 0) { wpc[wid] = pc0; wps[wid] = ps0; wpc[4+wid] = pc1; wps[4+wid] = ps1; }
    __syncthreads();
    if (tid == 0) {
        unsigned t0 = 0, t1 = 0; float s0 = 0.f, s1 = 0.f;
        for (int q = 0; q < 4; ++q) { t0 += wpc[q]; s0 += wps[q]; t1 += wpc[4+q]; s1 += wps[4+q]; }
        atomicAdd(&pcnt[b*2+0], t0); unsafeAtomicAdd(&psum[b*2+0], s0);
        atomicAdd(&pcnt[b*2+1], t1); unsafeAtomicAdd(&psum[b*2+1], s1);
    }
}

// ---------------------------------------------------------------------------
// counts-only block suffix select (256 threads)
// ---------------------------------------------------------------------------
template<int NBINS>
__device__ __forceinline__ void select_counts(
    const unsigned* __restrict__ cnt, unsigned k,
    unsigned& outBin, unsigned& outRem)
{
    constexpr int PER = NBINS / 256;
    const int t = threadIdx.x;
    unsigned lc[PER];
#pragma unroll
    for (int j = 0; j < PER; ++j) lc[j] = cnt[t*PER + j];
    unsigned lsum = 0;
#pragma unroll
    for (int j = 0; j < PER; ++j) lsum += lc[j];

    __shared__ unsigned part[256];
    __shared__ unsigned s_bin, s_rem;
    part[t] = lsum;
    __syncthreads();
    for (int off = 1; off < 256; off <<= 1) {
        unsigned v = (t + off < 256) ? part[t + off] : 0u;
        __syncthreads();
        part[t] += v;
        __syncthreads();
    }
    unsigned cum = (t + 1 < 256) ? part[t + 1] : 0u;
#pragma unroll
    for (int j = PER - 1; j >= 0; --j) {
        unsigned c = lc[j];
        if (cum < k && k <= cum + c) { s_bin = (unsigned)(t * PER + j); s_rem = k - cum; }
        cum += c;
    }
    __syncthreads();
    outBin = s_bin; outRem = s_rem;
}

template<int NBINS>
__device__ __forceinline__ void select_counts_sums(
    const unsigned* __restrict__ cnt, const float* __restrict__ sums,
    unsigned k, unsigned& outBin, unsigned& outRem, double& outSum)
{
    constexpr int PER = NBINS / 256;
    const int t = threadIdx.x;
    unsigned lc[PER]; float lf[PER];
#pragma unroll
    for (int j = 0; j < PER; ++j) { lc[j] = cnt[t*PER + j]; lf[j] = sums[t*PER + j]; }
    unsigned lsum = 0;
#pragma unroll
    for (int j = 0; j < PER; ++j) lsum += lc[j];

    __shared__ unsigned part[256];
    __shared__ unsigned s_bin, s_rem;
    __shared__ double   wsum[4];
    part[t] = lsum;
    __syncthreads();
    for (int off = 1; off < 256; off <<= 1) {
        unsigned v = (t + off < 256) ? part[t + off] : 0u;
        __syncthreads();
        part[t] += v;
        __syncthreads();
    }
    unsigned cum = (t + 1 < 256) ? part[t + 1] : 0u;
#pragma unroll
    for (int j = PER - 1; j >= 0; --j) {
        unsigned c = lc[j];
        if (cum < k && k <= cum + c) { s_bin = (unsigned)(t * PER + j); s_rem = k - cum; }
        cum += c;
    }
    __syncthreads();
    const unsigned bin = s_bin;
    double ds = 0.0;
#pragma unroll
    for (int j = 0; j < PER; ++j)
        if ((unsigned)(t * PER + j) > bin) ds += (double)lf[j];
    for (int o = 32; o > 0; o >>= 1) ds += __shfl_down(ds, o);
    const int wid = t >> 6, lane = t & 63;
    if (lane == 0) wsum[wid] = ds;
    __syncthreads();
    if (t == 0) ds = wsum[0] + wsum[1] + wsum[2] + wsum[3];
    outBin = bin; outRem = s_rem; outSum = ds;
}

__global__ __launch_bounds__(256) void k_scan1(
    const unsigned* __restrict__ h1c,
    const unsigned* __restrict__ pcnt, const float* __restrict__ psum,
    unsigned* __restrict__ T1, unsigned* __restrict__ rem1,
    unsigned* __restrict__ kk, float* __restrict__ posi)
{
    const int idx = blockIdx.x;
    const unsigned p  = pcnt[idx];
    const unsigned nn = (unsigned)NPS - p;
    const unsigned k  = p ? ((nn < 3u*p) ? nn : 3u*p) : TOPK_NO_POS;
    if (threadIdx.x == 0) {
        kk[idx]   = k;
        posi[idx] = p ? (psum[idx] / (float)p) : 0.0f;
    }
    if (k == 0u) {
        if (threadIdx.x == 0) { T1[idx] = 0xFFFFFFFFu; rem1[idx] = 0u; }
        return;
    }
    unsigned bin, rem;
    select_counts<512>(h1c + idx*512, k, bin, rem);
    if (threadIdx.x == 0) { T1[idx] = bin; rem1[idx] = rem; }
}

// ---------------------------------------------------------------------------
// Pass 2: register-sum above T1 bin, stage-2 count histogram, LDS-staged
// compaction of T1-bin elements.
// ---------------------------------------------------------------------------
__global__ __launch_bounds__(256, 4) void k_pass2(
    const float4* __restrict__ pred4,
    const float4* __restrict__ reg4,
    const float4* __restrict__ aff4,
    const float4* __restrict__ lossR4, const float4* __restrict__ lossA4, int haveLoss,
    const unsigned* __restrict__ T1,
    unsigned* __restrict__ h2c, double* __restrict__ sumAbove,
    float* __restrict__ cbuf, unsigned* __restrict__ ccnt)
{
    __shared__ unsigned sc0[2048], sc1[2048];
    __shared__ float    lb0[CAPB], lb1[CAPB];
    __shared__ unsigned lcnt[2];
    __shared__ unsigned sbase[2];
    __shared__ float    wred[8];
    for (int j = threadIdx.x; j < 2048; j += 256) { sc0[j] = 0u; sc1[j] = 0u; }
    if (threadIdx.x < 2) lcnt[threadIdx.x] = 0u;
    __syncthreads();

    const int b = blockIdx.y;
    const unsigned t1r = T1[b*2+0], t1a = T1[b*2+1];
    const int tid = threadIdx.x, lane = tid & 63;
    float*    gb0 = cbuf + (size_t)(b*2+0) * CAP;
    float*    gb1 = cbuf + (size_t)(b*2+1) * CAP;
    unsigned* gc0 = ccnt + b*2+0;
    unsigned* gc1 = ccnt + b*2+1;
    float rs0 = 0.f, rs1 = 0.f;

    // per-value: rs += v above bin; histogram+LDS-compact inside bin
    auto proc = [&](float v, unsigned t1, unsigned* sc, float& rs,
                    unsigned* lcnt_p, float* lbuf, unsigned* gcnt, float* gbuf) {
        if (v < 0.0f) return;                    // positive sentinel
        const unsigned bt  = __float_as_uint(v);
        const unsigned key = bt >> 21;
        if (key > t1) { rs += v; return; }
        if (key != t1) return;
        atomicAdd(&sc[(bt >> 10) & 2047u], 1u);
        // lanes active here are exactly the matched lanes of this wave
        const unsigned long long m = __ballot(true);
        const int ldr = __ffsll(m) - 1;
        const unsigned pre = (unsigned)__popcll(m & ((1ull << lane) - 1ull));
        unsigned base = 0;
        if (lane == ldr) base = atomicAdd(lcnt_p, (unsigned)__popcll(m));  // LDS
        base = __shfl(base, ldr);
        const unsigned ix = base + pre;
        if (ix < (unsigned)CAPB) lbuf[ix] = v;
        else { unsigned g = atomicAdd(gcnt, 1u); if (g < (unsigned)CAP) gbuf[g] = v; }
    };

    constexpr int ITERS = EPB / 1024;
    long idx4 = (((long)b * NPS + (long)blockIdx.x * EPB) >> 2) + tid;
    for (int i = 0; i < ITERS; ++i, idx4 += 256) {
        float4 vr, va;
        if (haveLoss) { vr = lossR4[idx4]; va = lossA4[idx4]; }
        else {
            const float4 r  = reg4[idx4];
            const float4 a  = aff4[idx4];
            const float4 pA = pred4[idx4*2];
            const float4 pB = pred4[idx4*2+1];
            float d;
            d = pA.x - r.x; vr.x = (r.x >= POS_THR_F) ? -1.0f : d*d;
            d = pA.z - r.y; vr.y = (r.y >= POS_THR_F) ? -1.0f : d*d;
            d = pB.x - r.z; vr.z = (r.z >= POS_THR_F) ? -1.0f : d*d;
            d = pB.z - r.w; vr.w = (r.w >= POS_THR_F) ? -1.0f : d*d;
            d = pA.y - a.x; va.x = (a.x >= POS_THR_F) ? -1.0f : d*d;
            d = pA.w - a.y; va.y = (a.y >= POS_THR_F) ? -1.0f : d*d;
            d = pB.y - a.z; va.z = (a.z >= POS_THR_F) ? -1.0f : d*d;
            d = pB.w - a.w; va.w = (a.w >= POS_THR_F) ? -1.0f : d*d;
        }
        proc(vr.x, t1r, sc0, rs0, &lcnt[0], lb0, gc0, gb0);
        proc(vr.y, t1r, sc0, rs0, &lcnt[0], lb0, gc0, gb0);
        proc(vr.z, t1r, sc0, rs0, &lcnt[0], lb0, gc0, gb0);
        proc(vr.w, t1r, sc0, rs0, &lcnt[0], lb0, gc0, gb0);
        proc(va.x, t1a, sc1, rs1, &lcnt[1], lb1, gc1, gb1);
        proc(va.y, t1a, sc1, rs1, &lcnt[1], lb1, gc1, gb1);
        proc(va.z, t1a, sc1, rs1, &lcnt[1], lb1, gc1, gb1);
        proc(va.w, t1a, sc1, rs1, &lcnt[1], lb1, gc1, gb1);
    }
    __syncthreads();

    // flush stage-2 histogram
    for (int j = tid; j < 2048; j += 256) {
        unsigned c0 = sc0[j];
        if (c0) atomicAdd(&h2c[(b*2+0)*2048 + j], c0);
        unsigned c1 = sc1[j];
        if (c1) atomicAdd(&h2c[(b*2+1)*2048 + j], c1);
    }
    // flush compact buffers: one global atomic per channel per block
    const unsigned lc0 = lcnt[0] < (unsigned)CAPB ? lcnt[0] : (unsigned)CAPB;
    const unsigned lc1 = lcnt[1] < (unsigned)CAPB ? lcnt[1] : (unsigned)CAPB;
    if (tid == 0)      sbase[0] = lc0 ? atomicAdd(gc0, lc0) : 0u;
    else if (tid == 1) sbase[1] = lc1 ? atomicAdd(gc1, lc1) : 0u;
    __syncthreads();
    for (unsigned i = tid; i < lc0; i += 256) {
        unsigned g = sbase[0] + i;
        if (g < (unsigned)CAP) gb0[g] = lb0[i];
    }
    for (unsigned i = tid; i < lc1; i += 256) {
        unsigned g = sbase[1] + i;
        if (g < (unsigned)CAP) gb1[g] = lb1[i];
    }
    // sum-above reduction
    for (int o = 32; o > 0; o >>= 1) { rs0 += __shfl_down(rs0, o); rs1 += __shfl_down(rs1, o); }
    const int wid = tid >> 6;
    if (lane == 0) { wred[wid] = rs0; wred[4+wid] = rs1; }
    __syncthreads();
    if (tid == 0) {
        float s0 = wred[0]+wred[1]+wred[2]+wred[3];
        float s1 = wred[4]+wred[5]+wred[6]+wred[7];
        unsafeAtomicAdd(&sumAbove[b*2+0], (double)s0);
        unsafeAtomicAdd(&sumAbove[b*2+1], (double)s1);
    }
}

__global__ __launch_bounds__(256) void k_scan2(
    const unsigned* __restrict__ h2c,
    const unsigned* __restrict__ T1, const unsigned* __restrict__ rem1,
    unsigned* __restrict__ T2, unsigned* __restrict__ rem2)
{
    const int idx = blockIdx.x;
    if (T1[idx] == 0xFFFFFFFFu) {
        if (threadIdx.x == 0) { T2[idx] = 0xFFFFFFFFu; rem2[idx] = 0u; }
        return;
    }
    unsigned bin, rem;
    select_counts<2048>(h2c + idx*2048, rem1[idx], bin, rem);
    if (threadIdx.x == 0) { T2[idx] = bin; rem2[idx] = rem; }
}

// ---------------------------------------------------------------------------
// Pass 3 (compact): per-channel; candidates all have key == T1 already.
// ---------------------------------------------------------------------------
__global__ __launch_bounds__(256) void k_pass3_compact(
    const float* __restrict__ cbuf, const unsigned* __restrict__ ccnt,
    const unsigned* __restrict__ T2,
    unsigned* __restrict__ h3c, float* __restrict__ h3s,
    double* __restrict__ sumMid)
{
    const int ch = blockIdx.x;
    const unsigned cnt = ccnt[ch];
    if (cnt > (unsigned)CAP) return;            // overflow -> k_pass3_full owns it
    __shared__ unsigned sc[1024];
    __shared__ float    ss[1024];
    __shared__ float    wred[4];
    for (int j = threadIdx.x; j < 1024; j += 256) { sc[j] = 0u; ss[j] = 0.f; }
    __syncthreads();

    const unsigned t2 = T2[ch];
    const float* buf = cbuf + (size_t)ch * CAP;
    float rs = 0.f;
    for (unsigned i = threadIdx.x; i < cnt; i += 256) {
        const float v = buf[i];
        const unsigned bt = __float_as_uint(v);
        const unsigned s2 = (bt >> 10) & 2047u;
        if (s2 > t2) rs += v;
        else if (s2 == t2) { atomicAdd(&sc[bt & 1023u], 1u); unsafeAtomicAdd(&ss[bt & 1023u], v); }
    }
    __syncthreads();
    for (int j = threadIdx.x; j < 1024; j += 256) {
        unsigned c = sc[j];
        if (c) { atomicAdd(&h3c[ch*1024 + j], c); unsafeAtomicAdd(&h3s[ch*1024 + j], ss[j]); }
    }
    for (int o = 32; o > 0; o >>= 1) rs += __shfl_down(rs, o);
    const int wid = threadIdx.x >> 6, lane = threadIdx.x & 63;
    if (lane == 0) wred[wid] = rs;
    __syncthreads();
    if (threadIdx.x == 0)
        unsafeAtomicAdd(&sumMid[ch], (double)(wred[0]+wred[1]+wred[2]+wred[3]));
}

// Fallback full scan: only for channels whose compact buffer overflowed.
// Normally every block early-exits after 2 scalar loads.
__global__ __launch_bounds__(256, 4) void k_pass3_full(
    const float4* __restrict__ pred4,
    const float4* __restrict__ reg4,
    const float4* __restrict__ aff4,
    const float4* __restrict__ lossR4, const float4* __restrict__ lossA4, int haveLoss,
    const unsigned* __restrict__ T1, const unsigned* __restrict__ T2,
    const unsigned* __restrict__ ccnt,
    unsigned* __restrict__ h3c, float* __restrict__ h3s,
    double* __restrict__ sumMid)
{
    const int b = blockIdx.y;
    const bool f0 = ccnt[b*2+0] > (unsigned)CAP;
    const bool f1 = ccnt[b*2+1] > (unsigned)CAP;
    if (!f0 && !f1) return;

    __shared__ unsigned sc0[1024], sc1[1024];
    __shared__ float    ss0[1024], ss1[1024];
    __shared__ float    wred[8];
    for (int j = threadIdx.x; j < 1024; j += 256) { sc0[j]=0u; sc1[j]=0u; ss0[j]=0.f; ss1[j]=0.f; }
    __syncthreads();

    const unsigned t1r = T1[b*2+0], t2r = T2[b*2+0];
    const unsigned t1a = T1[b*2+1], t2a = T2[b*2+1];
    const int tid = threadIdx.x;
    float rs0 = 0.f, rs1 = 0.f;

    constexpr int ITERS = EPB / 1024;
    long idx4 = (((long)b * NPS + (long)blockIdx.x * EPB) >> 2) + tid;
    for (int i = 0; i < ITERS; ++i, idx4 += 256) {
        float4 vr, va;
        if (haveLoss) { vr = lossR4[idx4]; va = lossA4[idx4]; }
        else {
            const float4 r  = reg4[idx4];
            const float4 a  = aff4[idx4];
            const float4 pA = pred4[idx4*2];
            const float4 pB = pred4[idx4*2+1];
            float d;
            d = pA.x - r.x; vr.x = (r.x >= POS_THR_F) ? -1.0f : d*d;
            d = pA.z - r.y; vr.y = (r.y >= POS_THR_F) ? -1.0f : d*d;
            d = pB.x - r.z; vr.z = (r.z >= POS_THR_F) ? -1.0f : d*d;
            d = pB.z - r.w; vr.w = (r.w >= POS_THR_F) ? -1.0f : d*d;
            d = pA.y - a.x; va.x = (a.x >= POS_THR_F) ? -1.0f : d*d;
            d = pA.w - a.y; va.y = (a.y >= POS_THR_F) ? -1.0f : d*d;
            d = pB.y - a.z; va.z = (a.z >= POS_THR_F) ? -1.0f : d*d;
            d = pB.w - a.w; va.w = (a.w >= POS_THR_F) ? -1.0f : d*d;
        }
#define DO3(V, T1V, T2V, SC, SS, RS, EN) do {                                 \
        if (EN && (V) >= 0.0f) { unsigned bt = __float_as_uint(V);            \
            if ((bt >> 21) == (T1V)) { unsigned s2 = (bt >> 10) & 2047u;      \
                if (s2 > (T2V)) RS += (V);                                    \
                else if (s2 == (T2V)) { atomicAdd(&SC[bt & 1023u], 1u);       \
                    unsafeAtomicAdd(&SS[bt & 1023u], (V)); } } } } while (0)
        DO3(vr.x, t1r, t2r, sc0, ss0, rs0, f0); DO3(vr.y, t1r, t2r, sc0, ss0, rs0, f0);
        DO3(vr.z, t1r, t2r, sc0, ss0, rs0, f0); DO3(vr.w, t1r, t2r, sc0, ss0, rs0, f0);
        DO3(va.x, t1a, t2a, sc1, ss1, rs1, f1); DO3(va.y, t1a, t2a, sc1, ss1, rs1, f1);
        DO3(va.z, t1a, t2a, sc1, ss1, rs1, f1); DO3(va.w, t1a, t2a, sc1, ss1, rs1, f1);
#undef DO3
    }
    __syncthreads();
    for (int j = tid; j < 1024; j += 256) {
        if (f0) { unsigned c = sc0[j];
            if (c) { atomicAdd(&h3c[(b*2+0)*1024 + j], c); unsafeAtomicAdd(&h3s[(b*2+0)*1024 + j], ss0[j]); } }
        if (f1) { unsigned c = sc1[j];
            if (c) { atomicAdd(&h3c[(b*2+1)*1024 + j], c); unsafeAtomicAdd(&h3s[(b*2+1)*1024 + j], ss1[j]); } }
    }
    for (int o = 32; o > 0; o >>= 1) { rs0 += __shfl_down(rs0, o); rs1 += __shfl_down(rs1, o); }
    const int wid = tid >> 6, lane = tid & 63;
    if (lane == 0) { wred[wid] = rs0; wred[4+wid] = rs1; }
    __syncthreads();
    if (tid == 0) {
        if (f0) unsafeAtomicAdd(&sumMid[b*2+0], (double)(wred[0]+wred[1]+wred[2]+wred[3]));
        if (f1) unsafeAtomicAdd(&sumMid[b*2+1], (double)(wred[4]+wred[5]+wred[6]+wred[7]));
    }
}

__global__ __launch_bounds__(256) void k_scan3(
    const unsigned* __restrict__ h3c, const float* __restrict__ h3s,
    const unsigned* __restrict__ T1, const unsigned* __restrict__ T2,
    const unsigned* __restrict__ rem2,
    const unsigned* __restrict__ kk, const float* __restrict__ posi,
    const double* __restrict__ sumAbove, const double* __restrict__ sumMid,
    float* __restrict__ contrib)
{
    const int idx = blockIdx.x;
    const unsigned k = kk[idx];
    if (k == 0u) {
        if (threadIdx.x == 0) contrib[idx] = posi[idx];
        return;
    }
    unsigned bin, rem; double s3;
    select_counts_sums<1024>(h3c + idx*1024, h3s + idx*1024, rem2[idx], bin, rem, s3);
    if (threadIdx.x == 0) {
        const float t = __uint_as_float((T1[idx] << 21) | (T2[idx] << 10) | bin);
        const double nega = (sumAbove[idx] + sumMid[idx] + s3 + (double)rem * (double)t)
                            / (double)k;
        contrib[idx] = (float)((double)posi[idx] + nega);
    }
}

__global__ void k_reduce(const float* __restrict__ contrib, float* __restrict__ out)
{
    double v = (double)contrib[threadIdx.x];
    for (int o = 32; o > 0; o >>= 1) v += __shfl_down(v, o);
    if (threadIdx.x == 0) out[0] = (float)(v / (double)BATCH);
}

// ---------------------------------------------------------------------------
extern "C" void kernel_launch(void* const* d_in, const int* in_sizes, int n_in,
                              void* d_out, int out_size, void* d_ws, size_t ws_size,
                              hipStream_t stream)
{
    (void)in_sizes; (void)n_in; (void)out_size; (void)ws_size;
    const float4* pred4 = (const float4*)d_in[0];
    const float4* reg4  = (const float4*)d_in[1];
    const float4* aff4  = (const float4*)d_in[2];

    char* w = (char*)d_ws;
    unsigned* h1c  = (unsigned*)w;                        // 64*512
    unsigned* h2c  = h1c + (size_t)CH2 * 512;             // 64*2048
    unsigned* h3c  = h2c + (size_t)CH2 * 2048;            // 64*1024
    float*    h3s  = (float*)(h3c + (size_t)CH2 * 1024);  // 64*1024
    unsigned* pcnt = (unsigned*)(h3s + (size_t)CH2 * 1024);
    float*    psum = (float*)(pcnt + CH2);
    unsigned* T1   = (unsigned*)(psum + CH2);
    unsigned* T2   = T1 + CH2;
    unsigned* rem1 = T2 + CH2;
    unsigned* rem2 = rem1 + CH2;
    unsigned* kk   = rem2 + CH2;
    float*    posi = (float*)(kk + CH2);
    float*    contrib = posi + CH2;
    unsigned* ccnt = (unsigned*)(contrib + CH2);
    double*   sumAbove = (double*)(ccnt + CH2);           // 8B aligned
    double*   sumMid   = sumAbove + CH2;
    const size_t hdr_bytes = (size_t)((char*)(sumMid + CH2) - w);   // ~1.2 MB

    const size_t loss_off   = (size_t)4 << 20;
    const size_t loss_bytes = (size_t)PIX_ALL * 2 * sizeof(float);  // 151 MB
    const int haveLoss = (ws_size >= loss_off + loss_bytes) ? 1 : 0;
    float4* lossR4 = (float4*)(w + loss_off);
    float4* lossA4 = (float4*)(w + loss_off + (size_t)PIX_ALL * sizeof(float));

    const size_t cbuf_off = haveLoss ? (loss_off + loss_bytes) : loss_off;
    float* cbuf = (float*)(w + cbuf_off);                 // 33.5 MB (fits: ws >= in+out)

    hipMemsetAsync(d_ws, 0, hdr_bytes, stream);

    dim3 grid(BX, BATCH);
    k_pass1<<<grid, 256, 0, stream>>>(pred4, reg4, aff4, h1c, pcnt, psum,
                                      lossR4, lossA4, haveLoss);
    k_scan1<<<CH2, 256, 0, stream>>>(h1c, pcnt, psum, T1, rem1, kk, posi);
    k_pass2<<<grid, 256, 0, stream>>>(pred4, reg4, aff4, lossR4, lossA4, haveLoss,
                                      T1, h2c, sumAbove, cbuf, ccnt);
    k_scan2<<<CH2, 256, 0, stream>>>(h2c, T1, rem1, T2, rem2);
    k_pass3_compact<<<CH2, 256, 0, stream>>>(cbuf, ccnt, T2, h3c, h3s, sumMid);
    k_pass3_full<<<grid, 256, 0, stream>>>(pred4, reg4, aff4, lossR4, lossA4, haveLoss,
                                           T1, T2, ccnt, h3c, h3s, sumMid);
    k_scan3<<<CH2, 256, 0, stream>>>(h3c, h3s, T1, T2, rem2, kk, posi,
                                     sumAbove, sumMid, contrib);
    k_reduce<<<1, 64, 0, stream>>>(contrib, (float*)d_out);
}